// Round 1
// baseline (136.551 us; speedup 1.0000x reference)
//
#include <hip/hip_runtime.h>

#define NEGV -1e30f

// Problem constants (fixed by setup_inputs)
constexpr int Bn = 8, Ci = 64, Hn = 64, Wn = 64, Co = 64;

// Tiling
constexpr int COB = 8;            // co per block
constexpr int HT  = 8;            // output rows per block
constexpr int XROWS = HT + 2;     // 10 staged rows (halo)
constexpr int XCOLS = Wn + 2;     // 66 staged cols (halo)
constexpr int XTILE = XROWS * XCOLS;  // 660 floats

__global__ __launch_bounds__(256, 2)
void maxconv_kernel(const float* __restrict__ x, const float* __restrict__ wt,
                    float* __restrict__ out) {
    __shared__ float xs[2][XROWS][XCOLS];

    const int tid = threadIdx.x;
    const int h0  = blockIdx.x * HT;
    const int co0 = blockIdx.y * COB;
    const int b   = blockIdx.z;

    const int r  = tid >> 5;          // 0..7 output row within tile
    const int wi = (tid & 31) * 2;    // 0,2,...,62 output col base (strip of 2)

    const float* xb = x + (size_t)b * Ci * Hn * Wn;

    // Staging index decode (3 elems/thread covers 660 < 768)
    int srow[3], scol[3];
    bool sact[3];
    float sreg[3];
#pragma unroll
    for (int k = 0; k < 3; k++) {
        int idx = tid + k * 256;
        sact[k] = (idx < XTILE);
        srow[k] = idx / XCOLS;
        scol[k] = idx % XCOLS;
    }

    auto stage_load = [&](int ci) {
#pragma unroll
        for (int k = 0; k < 3; k++) {
            float v = NEGV;
            if (sact[k]) {
                int gh = h0 - 1 + srow[k];
                int gw = scol[k] - 1;
                if (gh >= 0 && gh < Hn && gw >= 0 && gw < Wn)
                    v = xb[((size_t)ci * Hn + gh) * Wn + gw];
            }
            sreg[k] = v;
        }
    };
    auto stage_store = [&](int buf) {
#pragma unroll
        for (int k = 0; k < 3; k++) {
            if (sact[k])
                (&xs[buf][0][0])[srow[k] * XCOLS + scol[k]] = sreg[k];
        }
    };

    float acc[COB][2];
#pragma unroll
    for (int c = 0; c < COB; c++) { acc[c][0] = NEGV; acc[c][1] = NEGV; }

    stage_load(0);
    stage_store(0);
    __syncthreads();

    for (int ci = 0; ci < Ci; ci++) {
        const int buf = ci & 1;
        if (ci + 1 < Ci) stage_load(ci + 1);   // global loads in flight during compute

        // Read 3 rows x 4 cols of staged x (xs col w maps to global col w-1,
        // so window for output w covers xs cols w..w+2; strip p=0,1 -> wi..wi+3).
        float xv[3][4];
#pragma unroll
        for (int i = 0; i < 3; i++) {
            const float2* rowp = (const float2*)&xs[buf][r + i][wi];  // wi even -> 8B aligned
            float2 a = rowp[0];
            float2 bb = rowp[1];
            xv[i][0] = a.x; xv[i][1] = a.y; xv[i][2] = bb.x; xv[i][3] = bb.y;
        }

#pragma unroll
        for (int c = 0; c < COB; c++) {
            // Block-uniform address -> scalar loads (s_load_dwordx8 + dword)
            const float* wp = wt + ((size_t)(co0 + c) * Ci + ci) * 9;
            float w0 = wp[0], w1 = wp[1], w2 = wp[2];
            float w3 = wp[3], w4 = wp[4], w5 = wp[5];
            float w6 = wp[6], w7 = wp[7], w8 = wp[8];
#pragma unroll
            for (int p = 0; p < 2; p++) {
                float t0 = xv[0][p + 0] + w0;
                float t1 = xv[0][p + 1] + w1;
                float t2 = xv[0][p + 2] + w2;
                float t3 = xv[1][p + 0] + w3;
                float t4 = xv[1][p + 1] + w4;
                float t5 = xv[1][p + 2] + w5;
                float t6 = xv[2][p + 0] + w6;
                float t7 = xv[2][p + 1] + w7;
                float t8 = xv[2][p + 2] + w8;
                float a = acc[c][p];
                a = fmaxf(a, fmaxf(t0, t1));   // -> v_max3_f32
                a = fmaxf(a, fmaxf(t2, t3));
                a = fmaxf(a, fmaxf(t4, t5));
                a = fmaxf(a, fmaxf(t6, t7));
                a = fmaxf(a, t8);
                acc[c][p] = a;
            }
        }

        if (ci + 1 < Ci) stage_store((ci + 1) & 1);  // other buffer: safe before barrier
        __syncthreads();
    }

    // Write 8 co x 2 pixels, float2 coalesced pairs
#pragma unroll
    for (int c = 0; c < COB; c++) {
        size_t o = (((size_t)b * Co + co0 + c) * Hn + (h0 + r)) * Wn + wi;
        float2 v = make_float2(acc[c][0], acc[c][1]);
        *(float2*)(out + o) = v;
    }
}

extern "C" void kernel_launch(void* const* d_in, const int* in_sizes, int n_in,
                              void* d_out, int out_size, void* d_ws, size_t ws_size,
                              hipStream_t stream) {
    const float* x  = (const float*)d_in[0];
    const float* wt = (const float*)d_in[1];
    float* out = (float*)d_out;

    dim3 grid(Hn / HT, Co / COB, Bn);   // 8 x 8 x 8 = 512 blocks
    maxconv_kernel<<<grid, 256, 0, stream>>>(x, wt, out);
}

// Round 2
// 124.882 us; speedup vs baseline: 1.0934x; 1.0934x over previous
//
#include <hip/hip_runtime.h>

#define NEGV -1e30f

// Problem constants (fixed by setup_inputs)
constexpr int Bn = 8, Ci = 64, Hn = 64, Wn = 64, Co = 64;

// Tiling: wave = one output row (64 lanes = 64 cols); block = 4 waves = 4 rows.
// Each thread accumulates 8 co for its pixel. Grid = (Co/8, Hn/4, Bn) = 1024 blocks
// -> 4 blocks/CU, 16 waves/CU, no LDS, no barriers.
constexpr int COB = 8;
constexpr int HT  = 4;

__global__ __launch_bounds__(256, 4)
void maxconv_kernel(const float* __restrict__ x, const float* __restrict__ wt,
                    float* __restrict__ out) {
    const int lane = threadIdx.x & 63;
    const int wrow = threadIdx.x >> 6;                 // 0..3
    const int co0  = blockIdx.x * COB;
    const int h    = blockIdx.y * HT + wrow;           // wave-uniform output row
    const int b    = blockIdx.z;

    // Clamped column offsets (clamp keeps addresses in-bounds; value fixed by cndmask)
    const int cl = lane > 0      ? lane - 1 : 0;
    const int cr = lane < Wn - 1 ? lane + 1 : Wn - 1;
    const bool edgeL = (lane == 0);
    const bool edgeR = (lane == Wn - 1);
    const bool hasUp = (h > 0);        // wave-uniform
    const bool hasDn = (h < Hn - 1);   // wave-uniform

    float acc[COB];
#pragma unroll
    for (int c = 0; c < COB; c++) acc[c] = NEGV;

    // Row base for ci=0: x[b][0][h][0]; per-ci stride = Hn*Wn floats
    const float* p = x + ((size_t)b * Ci * Hn + h) * Wn;

    for (int ci = 0; ci < Ci; ci++, p += Hn * Wn) {
        // 3x3 window via 9 coalesced loads (L1-resident rows), edges -> NEG
        float lm1 = NEGV, xm1 = NEGV, rm1 = NEGV;
        float lp1 = NEGV, xp1 = NEGV, rp1 = NEGV;
        if (hasUp) { lm1 = p[cl - Wn]; xm1 = p[lane - Wn]; rm1 = p[cr - Wn]; }
        if (hasDn) { lp1 = p[cl + Wn]; xp1 = p[lane + Wn]; rp1 = p[cr + Wn]; }
        float l0 = p[cl], x0 = p[lane], r0 = p[cr];

        if (edgeL) { lm1 = NEGV; l0 = NEGV; lp1 = NEGV; }
        if (edgeR) { rm1 = NEGV; r0 = NEGV; rp1 = NEGV; }

#pragma unroll
        for (int c = 0; c < COB; c++) {
            // Block-uniform address -> scalar (s_load) weight reads
            const float* wp = wt + ((size_t)(co0 + c) * Ci + ci) * 9;
            float t0 = lm1 + wp[0];
            float t1 = xm1 + wp[1];
            float t2 = rm1 + wp[2];
            float t3 = l0  + wp[3];
            float t4 = x0  + wp[4];
            float t5 = r0  + wp[5];
            float t6 = lp1 + wp[6];
            float t7 = xp1 + wp[7];
            float t8 = rp1 + wp[8];
            float a = acc[c];
            a = fmaxf(a, fmaxf(t0, t1));   // v_max3_f32
            a = fmaxf(a, fmaxf(t2, t3));
            a = fmaxf(a, fmaxf(t4, t5));
            a = fmaxf(a, fmaxf(t6, t7));
            a = fmaxf(a, t8);
            acc[c] = a;
        }
    }

    // Store 8 co planes, fully coalesced (lane = col)
#pragma unroll
    for (int c = 0; c < COB; c++) {
        out[(((size_t)b * Co + co0 + c) * Hn + h) * Wn + lane] = acc[c];
    }
}

extern "C" void kernel_launch(void* const* d_in, const int* in_sizes, int n_in,
                              void* d_out, int out_size, void* d_ws, size_t ws_size,
                              hipStream_t stream) {
    const float* x  = (const float*)d_in[0];
    const float* wt = (const float*)d_in[1];
    float* out = (float*)d_out;

    // co-group fastest so adjacent blocks share identical x rows (L1/L2 locality)
    dim3 grid(Co / COB, Hn / HT, Bn);   // 8 x 16 x 8 = 1024 blocks
    maxconv_kernel<<<grid, 256, 0, stream>>>(x, wt, out);
}